// Round 1
// baseline (267.510 us; speedup 1.0000x reference)
//
#include <hip/hip_runtime.h>

#define BATCH 4096
#define DIM   512
#define NLBL  512
#define BIGF  1e4f
#define MARGIN 1.0f

#define BM 64
#define BN 64
#define KC 32

// ---------------- kernel 1: row L2-normalize ----------------
__global__ __launch_bounds__(256) void normalize_k(const float* __restrict__ emb,
                                                   float* __restrict__ Nf) {
    int wave = threadIdx.x >> 6;   // 0..3
    int lane = threadIdx.x & 63;
    int row  = blockIdx.x * 4 + wave;
    const float4* src = (const float4*)(emb + (size_t)row * DIM);
    float4*       dst = (float4*)(Nf + (size_t)row * DIM);
    float4 v0 = src[lane];
    float4 v1 = src[lane + 64];
    float ss = v0.x*v0.x + v0.y*v0.y + v0.z*v0.z + v0.w*v0.w
             + v1.x*v1.x + v1.y*v1.y + v1.z*v1.z + v1.w*v1.w;
    #pragma unroll
    for (int off = 1; off < 64; off <<= 1) ss += __shfl_xor(ss, off);
    float scale = 1.0f / fmaxf(sqrtf(ss), 1e-12f);
    v0.x *= scale; v0.y *= scale; v0.z *= scale; v0.w *= scale;
    v1.x *= scale; v1.y *= scale; v1.z *= scale; v1.w *= scale;
    dst[lane]      = v0;
    dst[lane + 64] = v1;
}

// ---------------- kernel 2: init hp/hn ----------------
__global__ void init_k(unsigned* __restrict__ hp, unsigned* __restrict__ hn) {
    int i = blockIdx.x * blockDim.x + threadIdx.x;
    if (i < BATCH) {
        hp[i] = 0u;                       // hardest_pos = 0.0f
        hn[i] = __float_as_uint(BIGF);    // hardest_neg = BIG
    }
}

// ---------------- kernel 3: fused sim + batch-hard mining ----------------
// 64x64 output tile per block; 256 threads, 4x4 micro-tile each.
// LDS tiles XOR-swizzled: float index = row*KC + ((k4 ^ ((row>>2)&7))*4 + (k&3))
__global__ __launch_bounds__(256) void mine_k(const float* __restrict__ Nf,
                                              const int* __restrict__ lab,
                                              unsigned* __restrict__ hp,
                                              unsigned* __restrict__ hn) {
    __shared__ float As[BM * KC];
    __shared__ float Bs[BN * KC];

    const int tid = threadIdx.x;
    const int i0 = blockIdx.y * BM;
    const int j0 = blockIdx.x * BN;
    const int tx = tid & 15;   // col group
    const int ty = tid >> 4;   // row group

    float acc[4][4] = {};

    const int srow = tid >> 3;   // 0..31
    const int sk4  = tid & 7;    // 0..7

    for (int kc = 0; kc < DIM; kc += KC) {
        #pragma unroll
        for (int h = 0; h < 2; ++h) {
            int r = srow + 32 * h;
            float4 va = *(const float4*)(Nf + (size_t)(i0 + r) * DIM + kc + sk4 * 4);
            float4 vb = *(const float4*)(Nf + (size_t)(j0 + r) * DIM + kc + sk4 * 4);
            int slot = sk4 ^ ((r >> 2) & 7);
            *(float4*)(As + r * KC + slot * 4) = va;
            *(float4*)(Bs + r * KC + slot * 4) = vb;
        }
        __syncthreads();

        #pragma unroll
        for (int k4 = 0; k4 < KC / 4; ++k4) {
            float4 a[4], b[4];
            #pragma unroll
            for (int r = 0; r < 4; ++r) {
                int row = ty * 4 + r;
                a[r] = *(const float4*)(As + row * KC + ((k4 ^ ((row >> 2) & 7)) << 2));
            }
            #pragma unroll
            for (int c = 0; c < 4; ++c) {
                int row = tx * 4 + c;
                b[c] = *(const float4*)(Bs + row * KC + ((k4 ^ ((row >> 2) & 7)) << 2));
            }
            #pragma unroll
            for (int r = 0; r < 4; ++r) {
                #pragma unroll
                for (int c = 0; c < 4; ++c) {
                    acc[r][c] += a[r].x * b[c].x;
                    acc[r][c] += a[r].y * b[c].y;
                    acc[r][c] += a[r].z * b[c].z;
                    acc[r][c] += a[r].w * b[c].w;
                }
            }
        }
        __syncthreads();
    }

    // epilogue: mask by labels/diagonal, reduce row-wise, merge atomically
    int lj[4], jg[4];
    #pragma unroll
    for (int c = 0; c < 4; ++c) {
        jg[c] = j0 + tx * 4 + c;
        lj[c] = lab[jg[c]];
    }

    #pragma unroll
    for (int r = 0; r < 4; ++r) {
        int ig  = i0 + ty * 4 + r;
        int lir = lab[ig];
        float pm = 0.0f, nm = BIGF;
        #pragma unroll
        for (int c = 0; c < 4; ++c) {
            float dist = fmaxf(1.0f - acc[r][c], 0.0f);
            bool same = (lir == lj[c]);
            if (same) {
                if (ig != jg[c]) pm = fmaxf(pm, dist);
            } else {
                nm = fminf(nm, dist);
            }
        }
        // reduce across the 16 lanes sharing this output row
        #pragma unroll
        for (int off = 1; off < 16; off <<= 1) {
            pm = fmaxf(pm, __shfl_xor(pm, off));
            nm = fminf(nm, __shfl_xor(nm, off));
        }
        if (tx == 0) {
            atomicMax(hp + ig, __float_as_uint(pm));
            atomicMin(hn + ig, __float_as_uint(nm));
        }
    }
}

// ---------------- kernel 4: finalize ----------------
__global__ __launch_bounds__(1024) void final_k(const int* __restrict__ lab,
                                                const unsigned* __restrict__ hp,
                                                const unsigned* __restrict__ hn,
                                                float* __restrict__ out) {
    __shared__ int   cnt[NLBL];
    __shared__ float ssum[16];
    __shared__ int   scnt[16];
    int t = threadIdx.x;
    for (int i = t; i < NLBL; i += 1024) cnt[i] = 0;
    __syncthreads();
    for (int i = t; i < BATCH; i += 1024) atomicAdd(&cnt[lab[i]], 1);
    __syncthreads();

    float lsum = 0.0f;
    int   lcnt = 0;
    for (int i = t; i < BATCH; i += 1024) {
        int c = cnt[lab[i]];
        bool valid = (c > 1) && (c < BATCH);
        if (valid) {
            float per = fmaxf(__uint_as_float(hp[i]) - __uint_as_float(hn[i]) + MARGIN, 0.0f);
            lsum += per;
            lcnt += 1;
        }
    }
    #pragma unroll
    for (int off = 1; off < 64; off <<= 1) {
        lsum += __shfl_xor(lsum, off);
        lcnt += __shfl_xor(lcnt, off);
    }
    int w = t >> 6;
    if ((t & 63) == 0) { ssum[w] = lsum; scnt[w] = lcnt; }
    __syncthreads();
    if (t == 0) {
        float s = 0.0f; int c2 = 0;
        #pragma unroll
        for (int i = 0; i < 16; ++i) { s += ssum[i]; c2 += scnt[i]; }
        out[0] = s / (float)max(c2, 1);
    }
}

// ---------------- launcher ----------------
extern "C" void kernel_launch(void* const* d_in, const int* in_sizes, int n_in,
                              void* d_out, int out_size, void* d_ws, size_t ws_size,
                              hipStream_t stream) {
    const float* emb = (const float*)d_in[0];
    const int*   lab = (const int*)d_in[1];

    char* base = (char*)d_ws;
    float*    Nf = (float*)base;                                   // 4096*512*4 = 8 MB
    unsigned* hp = (unsigned*)(base + (size_t)BATCH * DIM * 4);    // 16 KB
    unsigned* hn = hp + BATCH;                                     // 16 KB

    normalize_k<<<BATCH / 4, 256, 0, stream>>>(emb, Nf);
    init_k<<<(BATCH + 255) / 256, 256, 0, stream>>>(hp, hn);

    dim3 grid(BATCH / BN, BATCH / BM);
    mine_k<<<grid, 256, 0, stream>>>(Nf, lab, hp, hn);

    final_k<<<1, 1024, 0, stream>>>(lab, hp, hn, (float*)d_out);
}

// Round 2
// 47.462 us; speedup vs baseline: 5.6363x; 5.6363x over previous
//
#include <hip/hip_runtime.h>
#include <hip/hip_bf16.h>

#define BATCH 4096
#define DIM   512
#define NLBL  512
#define BIGF  1e4f
#define MARGIN 1.0f

#define BM 128        // tile (rows = cols)
#define BK 64         // bf16 elems per K-step
#define NT (BATCH/BM) // 32 tiles per dim
#define NPAIR (NT*(NT+1)/2)  // 528 upper-triangle blocks
#define KITERS (DIM/BK)      // 8

using f32x4  = __attribute__((ext_vector_type(4))) float;
using bf16x8 = __attribute__((ext_vector_type(8))) short;

__device__ __forceinline__ unsigned short f2bf(float x) {
    __hip_bfloat16 h = __float2bfloat16(x);
    return *reinterpret_cast<unsigned short*>(&h);
}

#define GLOAD16(gp, lp) \
    __builtin_amdgcn_global_load_lds((const __attribute__((address_space(1))) void*)(gp), \
                                     (__attribute__((address_space(3))) void*)(lp), 16, 0, 0)

// ---------------- kernel 1: row L2-normalize -> bf16 ----------------
__global__ __launch_bounds__(256) void normalize_k(const float* __restrict__ emb,
                                                   unsigned short* __restrict__ Hi) {
    int wave = threadIdx.x >> 6;
    int lane = threadIdx.x & 63;
    int row  = blockIdx.x * 4 + wave;
    const float4* src = (const float4*)(emb + (size_t)row * DIM);
    float4 v0 = src[lane * 2];
    float4 v1 = src[lane * 2 + 1];
    float ss = v0.x*v0.x + v0.y*v0.y + v0.z*v0.z + v0.w*v0.w
             + v1.x*v1.x + v1.y*v1.y + v1.z*v1.z + v1.w*v1.w;
    #pragma unroll
    for (int off = 1; off < 64; off <<= 1) ss += __shfl_xor(ss, off);
    float scale = 1.0f / fmaxf(sqrtf(ss), 1e-12f);
    bf16x8 o;
    o[0] = (short)f2bf(v0.x * scale);
    o[1] = (short)f2bf(v0.y * scale);
    o[2] = (short)f2bf(v0.z * scale);
    o[3] = (short)f2bf(v0.w * scale);
    o[4] = (short)f2bf(v1.x * scale);
    o[5] = (short)f2bf(v1.y * scale);
    o[6] = (short)f2bf(v1.z * scale);
    o[7] = (short)f2bf(v1.w * scale);
    *(bf16x8*)(Hi + (size_t)row * DIM + lane * 8) = o;
}

// ---------------- kernel 2: init hp/hn ----------------
__global__ void init_k(unsigned* __restrict__ hp, unsigned* __restrict__ hn) {
    int i = blockIdx.x * blockDim.x + threadIdx.x;
    if (i < BATCH) {
        hp[i] = 0u;
        hn[i] = __float_as_uint(BIGF);
    }
}

// ---------------- kernel 3: fused bf16 MFMA sim + batch-hard mining ----------------
// Upper-triangle 128x128 tiles. 4 waves (2x2), each wave a 64x64 sub-tile of
// 4x4 16x16x32 MFMA fragments. LDS tiles written by global_load_lds (linear
// dest) with pre-swizzled global source: phys chunk c' holds logical c'^(row&7).
__global__ __launch_bounds__(256) void mine_k(const unsigned short* __restrict__ Hi,
                                              const int* __restrict__ lab,
                                              unsigned* __restrict__ hp,
                                              unsigned* __restrict__ hn) {
    __shared__ __attribute__((aligned(16))) unsigned short As[BM * BK]; // 16 KB
    __shared__ __attribute__((aligned(16))) unsigned short Bs[BM * BK]; // 16 KB
    __shared__ float rowp[2][BM], rown[2][BM], colp[2][BM], coln[2][BM]; // 4 KB

    // XCD-aware swizzle (528 = 8*66, bijective)
    int p = (int)blockIdx.x;
    p = (p & 7) * (NPAIR / 8) + (p >> 3);
    // map p -> (bi <= bj)
    int bi = 0, rem = p;
    while (rem >= NT - bi) { rem -= NT - bi; ++bi; }
    int bj = bi + rem;
    const int i0 = bi * BM;
    const int j0 = bj * BM;

    const int tid  = threadIdx.x;
    const int w    = tid >> 6;      // wave 0..3
    const int lane = tid & 63;
    const int wr   = w >> 1;        // wave row 0..1
    const int wc   = w & 1;         // wave col 0..1
    const int l15  = lane & 15;
    const int lhi  = lane >> 4;     // 0..3
    const int l7   = lane & 7;

    // staging geometry: per wave-issue, 8 rows x 128B; lane l -> row +(l>>3), chunk l&7
    const int srow = lane >> 3;            // 0..7
    const int sc   = (lane & 7) ^ (srow & 7); // pre-swizzled logical 16B chunk

    f32x4 acc[4][4] = {};

    const char* HiB = (const char*)Hi;

    for (int t = 0; t < KITERS; ++t) {
        const size_t kb = (size_t)t * (BK * 2); // byte offset along K
        #pragma unroll
        for (int q = 0; q < 4; ++q) {
            int r8 = w * 32 + q * 8;           // base row of this wave-issue
            const char* ga = HiB + (size_t)(i0 + r8 + srow) * (DIM * 2) + kb + (sc << 4);
            const char* gb = HiB + (size_t)(j0 + r8 + srow) * (DIM * 2) + kb + (sc << 4);
            GLOAD16(ga, (char*)As + r8 * 128);
            GLOAD16(gb, (char*)Bs + r8 * 128);
        }
        __syncthreads();   // drains vmcnt -> LDS tiles ready

        #pragma unroll
        for (int kk = 0; kk < 2; ++kk) {
            bf16x8 a[4], b[4];
            #pragma unroll
            for (int m = 0; m < 4; ++m) {
                int row = wr * 64 + m * 16 + l15;
                int cp  = ((kk * 4 + lhi) ^ l7);
                a[m] = *(const bf16x8*)((const char*)As + row * 128 + (cp << 4));
            }
            #pragma unroll
            for (int n = 0; n < 4; ++n) {
                int row = wc * 64 + n * 16 + l15;
                int cp  = ((kk * 4 + lhi) ^ l7);
                b[n] = *(const bf16x8*)((const char*)Bs + row * 128 + (cp << 4));
            }
            #pragma unroll
            for (int m = 0; m < 4; ++m)
                #pragma unroll
                for (int n = 0; n < 4; ++n)
                    acc[m][n] = __builtin_amdgcn_mfma_f32_16x16x32_bf16(a[m], b[n], acc[m][n], 0, 0, 0);
        }
        __syncthreads();   // protect LDS before next stage
    }

    // ---- epilogue ----
    // C[i][j]: i = i0 + wr*64 + m*16 + lhi*4 + r ; j = j0 + wc*64 + n*16 + l15
    int lj[4];
    #pragma unroll
    for (int n = 0; n < 4; ++n) lj[n] = lab[j0 + wc * 64 + n * 16 + l15];
    int li[16];
    #pragma unroll
    for (int m = 0; m < 4; ++m)
        #pragma unroll
        for (int r = 0; r < 4; ++r)
            li[m * 4 + r] = lab[i0 + wr * 64 + m * 16 + lhi * 4 + r];

    // row pass: reduce over j (cols) -> hp/hn[i]
    #pragma unroll
    for (int m = 0; m < 4; ++m) {
        #pragma unroll
        for (int r = 0; r < 4; ++r) {
            int i   = i0 + wr * 64 + m * 16 + lhi * 4 + r;
            int lir = li[m * 4 + r];
            float pm = 0.0f, nm = BIGF;
            #pragma unroll
            for (int n = 0; n < 4; ++n) {
                float dist = fmaxf(1.0f - acc[m][n][r], 0.0f);
                int j = j0 + wc * 64 + n * 16 + l15;
                if (lir == lj[n]) {
                    if (i != j) pm = fmaxf(pm, dist);
                } else {
                    nm = fminf(nm, dist);
                }
            }
            #pragma unroll
            for (int off = 1; off < 16; off <<= 1) {
                pm = fmaxf(pm, __shfl_xor(pm, off));
                nm = fminf(nm, __shfl_xor(nm, off));
            }
            if (l15 == 0) {
                int loc = wr * 64 + m * 16 + lhi * 4 + r;
                rowp[wc][loc] = pm;
                rown[wc][loc] = nm;
            }
        }
    }

    // col pass: reduce over i (rows) -> hp/hn[j]  (symmetry)
    #pragma unroll
    for (int n = 0; n < 4; ++n) {
        int j   = j0 + wc * 64 + n * 16 + l15;
        int ljn = lj[n];
        float cp = 0.0f, cn = BIGF;
        #pragma unroll
        for (int m = 0; m < 4; ++m) {
            #pragma unroll
            for (int r = 0; r < 4; ++r) {
                float dist = fmaxf(1.0f - acc[m][n][r], 0.0f);
                int i = i0 + wr * 64 + m * 16 + lhi * 4 + r;
                if (li[m * 4 + r] == ljn) {
                    if (i != j) cp = fmaxf(cp, dist);
                } else {
                    cn = fminf(cn, dist);
                }
            }
        }
        #pragma unroll
        for (int off = 16; off < 64; off <<= 1) {
            cp = fmaxf(cp, __shfl_xor(cp, off));
            cn = fminf(cn, __shfl_xor(cn, off));
        }
        if (lhi == 0) {
            int loc = wc * 64 + n * 16 + l15;
            colp[wr][loc] = cp;
            coln[wr][loc] = cn;
        }
    }

    __syncthreads();

    if (tid < BM) {
        float pmv = fmaxf(rowp[0][tid], rowp[1][tid]);
        float nmv = fminf(rown[0][tid], rown[1][tid]);
        atomicMax(hp + i0 + tid, __float_as_uint(pmv));
        atomicMin(hn + i0 + tid, __float_as_uint(nmv));
    } else {
        int c = tid - BM;
        float pmv = fmaxf(colp[0][c], colp[1][c]);
        float nmv = fminf(coln[0][c], coln[1][c]);
        atomicMax(hp + j0 + c, __float_as_uint(pmv));
        atomicMin(hn + j0 + c, __float_as_uint(nmv));
    }
}

// ---------------- kernel 4: finalize ----------------
__global__ __launch_bounds__(1024) void final_k(const int* __restrict__ lab,
                                                const unsigned* __restrict__ hp,
                                                const unsigned* __restrict__ hn,
                                                float* __restrict__ out) {
    __shared__ int   cnt[NLBL];
    __shared__ float ssum[16];
    __shared__ int   scnt[16];
    int t = threadIdx.x;
    for (int i = t; i < NLBL; i += 1024) cnt[i] = 0;
    __syncthreads();
    for (int i = t; i < BATCH; i += 1024) atomicAdd(&cnt[lab[i]], 1);
    __syncthreads();

    float lsum = 0.0f;
    int   lcnt = 0;
    for (int i = t; i < BATCH; i += 1024) {
        int c = cnt[lab[i]];
        if ((c > 1) && (c < BATCH)) {
            float per = fmaxf(__uint_as_float(hp[i]) - __uint_as_float(hn[i]) + MARGIN, 0.0f);
            lsum += per;
            lcnt += 1;
        }
    }
    #pragma unroll
    for (int off = 1; off < 64; off <<= 1) {
        lsum += __shfl_xor(lsum, off);
        lcnt += __shfl_xor(lcnt, off);
    }
    int w = t >> 6;
    if ((t & 63) == 0) { ssum[w] = lsum; scnt[w] = lcnt; }
    __syncthreads();
    if (t == 0) {
        float s = 0.0f; int c2 = 0;
        #pragma unroll
        for (int i = 0; i < 16; ++i) { s += ssum[i]; c2 += scnt[i]; }
        out[0] = s / (float)max(c2, 1);
    }
}

// ---------------- launcher ----------------
extern "C" void kernel_launch(void* const* d_in, const int* in_sizes, int n_in,
                              void* d_out, int out_size, void* d_ws, size_t ws_size,
                              hipStream_t stream) {
    const float* emb = (const float*)d_in[0];
    const int*   lab = (const int*)d_in[1];

    char* base = (char*)d_ws;
    unsigned short* Hi = (unsigned short*)base;                       // 4 MB
    unsigned* hp = (unsigned*)(base + (size_t)BATCH * DIM * 2);       // 16 KB
    unsigned* hn = hp + BATCH;                                        // 16 KB

    normalize_k<<<BATCH / 4, 256, 0, stream>>>(emb, Hi);
    init_k<<<(BATCH + 255) / 256, 256, 0, stream>>>(hp, hn);
    mine_k<<<NPAIR, 256, 0, stream>>>(Hi, lab, hp, hn);
    final_k<<<1, 1024, 0, stream>>>(lab, hp, hn, (float*)d_out);
}

// Round 3
// 42.277 us; speedup vs baseline: 6.3275x; 1.1226x over previous
//
#include <hip/hip_runtime.h>
#include <hip/hip_bf16.h>

#define BATCH 4096
#define DIM   512
#define NLBL  512
#define BIGF  1e4f
#define MARGIN 1.0f

#define BM 128        // tile (rows = cols)
#define BK 64         // bf16 elems per K-step
#define NT (BATCH/BM) // 32 tiles per dim
#define NPAIR (NT*(NT+1)/2)  // 528 upper-triangle blocks
#define KITERS (DIM/BK)      // 8

using f32x4  = __attribute__((ext_vector_type(4))) float;
using bf16x8 = __attribute__((ext_vector_type(8))) short;

__device__ __forceinline__ unsigned short f2bf(float x) {
    __hip_bfloat16 h = __float2bfloat16(x);
    return *reinterpret_cast<unsigned short*>(&h);
}

#define GLOAD16(gp, lp) \
    __builtin_amdgcn_global_load_lds((const __attribute__((address_space(1))) void*)(gp), \
                                     (__attribute__((address_space(3))) void*)(lp), 16, 0, 0)

// ---------------- kernel 1: row L2-normalize -> bf16 (+ hp/hn init fused) ----------------
__global__ __launch_bounds__(256) void normalize_k(const float* __restrict__ emb,
                                                   unsigned short* __restrict__ Hi,
                                                   unsigned* __restrict__ hp,
                                                   unsigned* __restrict__ hn) {
    int wave = threadIdx.x >> 6;
    int lane = threadIdx.x & 63;
    int row  = blockIdx.x * 4 + wave;
    const float4* src = (const float4*)(emb + (size_t)row * DIM);
    float4 v0 = src[lane * 2];
    float4 v1 = src[lane * 2 + 1];
    float ss = v0.x*v0.x + v0.y*v0.y + v0.z*v0.z + v0.w*v0.w
             + v1.x*v1.x + v1.y*v1.y + v1.z*v1.z + v1.w*v1.w;
    #pragma unroll
    for (int off = 1; off < 64; off <<= 1) ss += __shfl_xor(ss, off);
    float scale = 1.0f / fmaxf(sqrtf(ss), 1e-12f);
    bf16x8 o;
    o[0] = (short)f2bf(v0.x * scale);
    o[1] = (short)f2bf(v0.y * scale);
    o[2] = (short)f2bf(v0.z * scale);
    o[3] = (short)f2bf(v0.w * scale);
    o[4] = (short)f2bf(v1.x * scale);
    o[5] = (short)f2bf(v1.y * scale);
    o[6] = (short)f2bf(v1.z * scale);
    o[7] = (short)f2bf(v1.w * scale);
    *(bf16x8*)(Hi + (size_t)row * DIM + lane * 8) = o;
    if (lane == 0) {                      // fused init (one wave per row)
        hp[row] = 0u;
        hn[row] = __float_as_uint(BIGF);
    }
}

// ---------------- kernel 2: fused bf16 MFMA sim + batch-hard mining ----------------
// Upper-triangle 128x128 tiles, double-buffered LDS, 1 barrier per K-step.
// 4 waves (2x2), each wave 64x64 = 4x4 fragments of 16x16x32 MFMA.
__global__ __launch_bounds__(256) void mine_k(const unsigned short* __restrict__ Hi,
                                              const int* __restrict__ lab,
                                              unsigned* __restrict__ hp,
                                              unsigned* __restrict__ hn) {
    __shared__ __attribute__((aligned(16))) unsigned short As[2][BM * BK]; // 32 KB
    __shared__ __attribute__((aligned(16))) unsigned short Bs[2][BM * BK]; // 32 KB
    __shared__ float rowp[2][BM], rown[2][BM], colp[2][BM], coln[2][BM];   // 4 KB

    // XCD-aware swizzle (528 = 8*66, bijective)
    int p = (int)blockIdx.x;
    p = (p & 7) * (NPAIR / 8) + (p >> 3);
    int bi = 0, rem = p;
    while (rem >= NT - bi) { rem -= NT - bi; ++bi; }
    int bj = bi + rem;
    const int i0 = bi * BM;
    const int j0 = bj * BM;

    const int tid  = threadIdx.x;
    const int w    = tid >> 6;
    const int lane = tid & 63;
    const int wr   = w >> 1;
    const int wc   = w & 1;
    const int l15  = lane & 15;
    const int lhi  = lane >> 4;
    const int l7   = lane & 7;

    const int srow = lane >> 3;               // 0..7
    const int sc   = (lane & 7) ^ (srow & 7); // pre-swizzled 16B chunk

    // hoist label loads (overlap with staging latency)
    int lj[4];
    #pragma unroll
    for (int n = 0; n < 4; ++n) lj[n] = lab[j0 + wc * 64 + n * 16 + l15];
    int li[16];
    #pragma unroll
    for (int m = 0; m < 4; ++m)
        #pragma unroll
        for (int r = 0; r < 4; ++r)
            li[m * 4 + r] = lab[i0 + wr * 64 + m * 16 + lhi * 4 + r];

    f32x4 acc[4][4] = {};
    const char* HiB = (const char*)Hi;

    auto STAGE = [&](int buf, int t) {
        const size_t kb = (size_t)t * (BK * 2);
        #pragma unroll
        for (int q = 0; q < 4; ++q) {
            int r8 = w * 32 + q * 8;
            const char* ga = HiB + (size_t)(i0 + r8 + srow) * (DIM * 2) + kb + (sc << 4);
            const char* gb = HiB + (size_t)(j0 + r8 + srow) * (DIM * 2) + kb + (sc << 4);
            GLOAD16(ga, (char*)As[buf] + r8 * 128);
            GLOAD16(gb, (char*)Bs[buf] + r8 * 128);
        }
    };
    auto COMPUTE = [&](int buf) {
        #pragma unroll
        for (int kk = 0; kk < 2; ++kk) {
            bf16x8 a[4], b[4];
            #pragma unroll
            for (int m = 0; m < 4; ++m) {
                int row = wr * 64 + m * 16 + l15;
                int cp  = ((kk * 4 + lhi) ^ l7);
                a[m] = *(const bf16x8*)((const char*)As[buf] + row * 128 + (cp << 4));
            }
            #pragma unroll
            for (int n = 0; n < 4; ++n) {
                int row = wc * 64 + n * 16 + l15;
                int cp  = ((kk * 4 + lhi) ^ l7);
                b[n] = *(const bf16x8*)((const char*)Bs[buf] + row * 128 + (cp << 4));
            }
            #pragma unroll
            for (int m = 0; m < 4; ++m)
                #pragma unroll
                for (int n = 0; n < 4; ++n)
                    acc[m][n] = __builtin_amdgcn_mfma_f32_16x16x32_bf16(a[m], b[n], acc[m][n], 0, 0, 0);
        }
    };

    // ---- 2-phase pipelined K-loop: 1 barrier per step, loads in flight during compute ----
    STAGE(0, 0);
    __syncthreads();
    #pragma unroll
    for (int t = 0; t < KITERS - 1; ++t) {
        const int cur = t & 1;
        STAGE(cur ^ 1, t + 1);                 // issue next tile's loads first
        __builtin_amdgcn_sched_barrier(0);     // keep issue before compute
        COMPUTE(cur);
        __syncthreads();                       // drains vmcnt -> next buffer ready
    }
    COMPUTE((KITERS - 1) & 1);

    // ---- epilogue ----
    // C[i][j]: i = i0 + wr*64 + m*16 + lhi*4 + r ; j = j0 + wc*64 + n*16 + l15
    #pragma unroll
    for (int m = 0; m < 4; ++m) {
        #pragma unroll
        for (int r = 0; r < 4; ++r) {
            int i   = i0 + wr * 64 + m * 16 + lhi * 4 + r;
            int lir = li[m * 4 + r];
            float pm = 0.0f, nm = BIGF;
            #pragma unroll
            for (int n = 0; n < 4; ++n) {
                float dist = fmaxf(1.0f - acc[m][n][r], 0.0f);
                int j = j0 + wc * 64 + n * 16 + l15;
                if (lir == lj[n]) {
                    if (i != j) pm = fmaxf(pm, dist);
                } else {
                    nm = fminf(nm, dist);
                }
            }
            #pragma unroll
            for (int off = 1; off < 16; off <<= 1) {
                pm = fmaxf(pm, __shfl_xor(pm, off));
                nm = fminf(nm, __shfl_xor(nm, off));
            }
            if (l15 == 0) {
                int loc = wr * 64 + m * 16 + lhi * 4 + r;
                rowp[wc][loc] = pm;
                rown[wc][loc] = nm;
            }
        }
    }

    #pragma unroll
    for (int n = 0; n < 4; ++n) {
        int j   = j0 + wc * 64 + n * 16 + l15;
        int ljn = lj[n];
        float cp = 0.0f, cn = BIGF;
        #pragma unroll
        for (int m = 0; m < 4; ++m) {
            #pragma unroll
            for (int r = 0; r < 4; ++r) {
                float dist = fmaxf(1.0f - acc[m][n][r], 0.0f);
                int i = i0 + wr * 64 + m * 16 + lhi * 4 + r;
                if (li[m * 4 + r] == ljn) {
                    if (i != j) cp = fmaxf(cp, dist);
                } else {
                    cn = fminf(cn, dist);
                }
            }
        }
        #pragma unroll
        for (int off = 16; off < 64; off <<= 1) {
            cp = fmaxf(cp, __shfl_xor(cp, off));
            cn = fminf(cn, __shfl_xor(cn, off));
        }
        if (lhi == 0) {
            int loc = wc * 64 + n * 16 + l15;
            colp[wr][loc] = cp;
            coln[wr][loc] = cn;
        }
    }

    __syncthreads();

    if (tid < BM) {
        float pmv = fmaxf(rowp[0][tid], rowp[1][tid]);
        float nmv = fminf(rown[0][tid], rown[1][tid]);
        atomicMax(hp + i0 + tid, __float_as_uint(pmv));
        atomicMin(hn + i0 + tid, __float_as_uint(nmv));
    } else {
        int c = tid - BM;
        float pmv = fmaxf(colp[0][c], colp[1][c]);
        float nmv = fminf(coln[0][c], coln[1][c]);
        atomicMax(hp + j0 + c, __float_as_uint(pmv));
        atomicMin(hn + j0 + c, __float_as_uint(nmv));
    }
}

// ---------------- kernel 3: finalize ----------------
__global__ __launch_bounds__(1024) void final_k(const int* __restrict__ lab,
                                                const unsigned* __restrict__ hp,
                                                const unsigned* __restrict__ hn,
                                                float* __restrict__ out) {
    __shared__ int   cnt[NLBL];
    __shared__ float ssum[16];
    __shared__ int   scnt[16];
    int t = threadIdx.x;
    for (int i = t; i < NLBL; i += 1024) cnt[i] = 0;
    __syncthreads();
    for (int i = t; i < BATCH; i += 1024) atomicAdd(&cnt[lab[i]], 1);
    __syncthreads();

    float lsum = 0.0f;
    int   lcnt = 0;
    for (int i = t; i < BATCH; i += 1024) {
        int c = cnt[lab[i]];
        if ((c > 1) && (c < BATCH)) {
            float per = fmaxf(__uint_as_float(hp[i]) - __uint_as_float(hn[i]) + MARGIN, 0.0f);
            lsum += per;
            lcnt += 1;
        }
    }
    #pragma unroll
    for (int off = 1; off < 64; off <<= 1) {
        lsum += __shfl_xor(lsum, off);
        lcnt += __shfl_xor(lcnt, off);
    }
    int w = t >> 6;
    if ((t & 63) == 0) { ssum[w] = lsum; scnt[w] = lcnt; }
    __syncthreads();
    if (t == 0) {
        float s = 0.0f; int c2 = 0;
        #pragma unroll
        for (int i = 0; i < 16; ++i) { s += ssum[i]; c2 += scnt[i]; }
        out[0] = s / (float)max(c2, 1);
    }
}

// ---------------- launcher ----------------
extern "C" void kernel_launch(void* const* d_in, const int* in_sizes, int n_in,
                              void* d_out, int out_size, void* d_ws, size_t ws_size,
                              hipStream_t stream) {
    const float* emb = (const float*)d_in[0];
    const int*   lab = (const int*)d_in[1];

    char* base = (char*)d_ws;
    unsigned short* Hi = (unsigned short*)base;                       // 4 MB
    unsigned* hp = (unsigned*)(base + (size_t)BATCH * DIM * 2);       // 16 KB
    unsigned* hn = hp + BATCH;                                        // 16 KB

    normalize_k<<<BATCH / 4, 256, 0, stream>>>(emb, Hi, hp, hn);
    mine_k<<<NPAIR, 256, 0, stream>>>(Hi, lab, hp, hn);
    final_k<<<1, 1024, 0, stream>>>(lab, hp, hn, (float*)d_out);
}